// Round 6
// baseline (146.495 us; speedup 1.0000x reference)
//
#include <hip/hip_runtime.h>

// Problem constants (from reference)
#define T_TREES 200
#define BATCH   2048
#define D_FEAT  512
#define N_NODE  64
#define LR      0.01f

typedef __attribute__((__ext_vector_type__(8)))  __bf16 bf16x8;
typedef __attribute__((__ext_vector_type__(16))) float  f32x16;

__device__ __forceinline__ unsigned short f32_to_bf16(float f) {
    unsigned u = __float_as_uint(f);
    u += 0x7FFFu + ((u >> 16) & 1u);   // RNE
    return (unsigned short)(u >> 16);
}

__device__ __forceinline__ void gload_lds16(const void* g, void* l) {
    __builtin_amdgcn_global_load_lds(
        (__attribute__((address_space(1))) void*)(void*)g,
        (__attribute__((address_space(3))) void*)l,
        16, 0, 0);
}

// ---------------- fused prep kernel ----------------
// kg-major layouts so main-kernel access is contiguous:
// x_p[mt 16][kg 64][m 128][8k] bf16 ; w_p[pair 100][kg 64][n' 128][8k] bf16 ;
// w_dt[t 200][32 node][64 n] bf16.
// Grid 3456: [0,256) prep_x | [256,1856) prep_wt | [1856,3456) prep_wd.
__global__ __launch_bounds__(256) void prep_all(
    const float* __restrict__ x, const float* __restrict__ w_t,
    const float* __restrict__ w_d,
    unsigned short* __restrict__ x_p, unsigned short* __restrict__ w_p,
    unsigned short* __restrict__ w_dt) {
    __shared__ float tile[64 * 65];
    int b = blockIdx.x;
    if (b < 256) {
        // ---- x [2048][512] f32 -> x_p ----
        int mb = b >> 3, slab = b & 7;
        const float* src = x + (mb * 64) * D_FEAT + slab * 64;
        #pragma unroll
        for (int p = 0; p < 16; ++p) {
            int idx = p * 256 + threadIdx.x;
            int r = idx >> 6, c = idx & 63;
            tile[r * 65 + c] = src[r * D_FEAT + c];
        }
        __syncthreads();
        int mt = mb >> 1, mq = mb & 1;
        unsigned short* dst = x_p + mt * 65536 + slab * 8192 + mq * 512;
        #pragma unroll
        for (int p = 0; p < 2; ++p) {
            int sid = p * 256 + threadIdx.x;   // 0..511
            int kgl = sid >> 6;                 // 0..7
            int r   = sid & 63;
            const float* sr = &tile[r * 65 + kgl * 8];
            bf16x8 o;
            #pragma unroll
            for (int j = 0; j < 8; ++j) o[j] = (__bf16)sr[j];
            *(bf16x8*)(dst + kgl * 1024 + r * 8) = o;
        }
    } else if (b < 1856) {
        // ---- w_t [t][d][n] f32 -> w_p (pair-interleaved, kg-major) ----
        int bb = b - 256;
        int t = bb >> 3, slab = bb & 7;
        const float* src = w_t + t * (D_FEAT * N_NODE) + slab * 64 * N_NODE;
        #pragma unroll
        for (int p = 0; p < 16; ++p) {
            int idx = p * 256 + threadIdx.x;
            int d = idx >> 6, n = idx & 63;
            tile[d * 65 + n] = src[d * N_NODE + n];
        }
        __syncthreads();
        unsigned short* dst = w_p + (t >> 1) * 65536 + slab * 8192 + (t & 1) * 512;
        #pragma unroll
        for (int p = 0; p < 2; ++p) {
            int sid = p * 256 + threadIdx.x;   // 0..511
            int kgl = sid >> 6;                 // 0..7
            int n   = sid & 63;
            bf16x8 o;
            #pragma unroll
            for (int j = 0; j < 8; ++j) o[j] = (__bf16)tile[(kgl * 8 + j) * 65 + n];
            *(bf16x8*)(dst + kgl * 1024 + n * 8) = o;
        }
    } else {
        // ---- w_d [t][n][15] f32 -> w_dt [t][32][64] (rows 15..31 zero) ----
        int i = (b - 1856) * 256 + threadIdx.x;          // 409600 = 200*32*64
        int n = i & 63;
        int l = (i >> 6) & 31;
        int t = i >> 11;
        float v = (l < 15) ? w_d[(t * 64 + n) * 15 + l] : 0.f;
        w_dt[i] = f32_to_bf16(v);
    }
}

// ---------------- main fused kernel ----------------
// 8-PHASE-CLASS STRUCTURE (r0-r4 post-mortem: every 2-barrier-per-chunk
// schedule pinned at 45.2 µs / MfmaUtil 25%; per-chunk interval ~5200 cyc
// vs 256 cyc MFMA = m233's stage+vmcnt+barrier critical path).
// Block = 512 threads (8 waves, 4M x 2N), 2 trees x 256 batch rows.
// K-tiles of BK=64 (8 total). Per K-tile per wave: 16 MFMA + 16
// ds_read_b128 between barriers (4 ks sub-phases, compiler-pipelined),
// setprio(1) around the cluster (T5: 8 waves in role-split phases).
// 3 x 48 KB LDS K-tile buffers (A slab0 16K | A slab1 16K | B 16K, all
// linear via global_load_lds); counted vmcnt(6): the next K-tile's 6
// loads stay in flight ACROSS every barrier (T4) - never drained to 0
// in the main loop. Stage target = buffer read 1 iter ago (readers
// provably done at the barrier). LDS 147456 -> 1 block/CU, 2 waves/SIMD;
// per-interval per-SIMD: 1024 cyc MFMA vs ~400 cyc staging -> MFMA-bound.
__global__ __launch_bounds__(512, 2) void gbdt_main(
    const unsigned short* __restrict__ x_p,    // [16][64][128][8] bf16
    const unsigned short* __restrict__ w_p,    // [100][64][128][8] bf16
    const unsigned short* __restrict__ w_dt,   // [200][32][64] bf16
    const float* __restrict__ b_t,             // [200][64]
    const float* __restrict__ b_d,             // [200][15]
    const float* __restrict__ w_l,             // [200][16]
    const float* __restrict__ b_l,             // [200]
    float* __restrict__ f_ws)                  // [2048][200]  (b-major)
{
    // LDS: 3 K-tile buffers at 0/49152/98304, each 48 KB:
    //   [A slab0 16384][A slab1 16384][B 16384], all [8 kg][128 r][8 k] bf16.
    // Overlays after GEMM1: H [0,69632) = [2 tree][256 m][68 col] bf16
    // (136 B stride: 2-way bank alias on GEMM2 frag reads = free);
    // P [0,69632) = [2][256][17] f32.
    __shared__ alignas(16) char smem[147456];
    unsigned short* Hs = (unsigned short*)smem;
    __bf16*         Hb = (__bf16*)smem;
    float*          Pf = (float*)smem;

    const int tid    = threadIdx.x;
    const int lane   = tid & 63;
    const int w      = tid >> 6;      // 0..7
    const int lane31 = lane & 31;
    const int kh     = lane >> 5;
    const int wm     = w >> 1;        // 64-row band (0..3)
    const int wn     = w & 1;         // tree-in-pair (0/1)

    const int xcd  = blockIdx.x & 7;
    const int slot = blockIdx.x >> 3;     // 0..103
    const int mt8  = slot & 7;            // 256-row tile
    const int pj   = slot >> 3;           // 0..12
    const int pair = xcd * 13 + pj;
    if (pair >= 100) return;
    const int t0 = pair * 2;
    const int m0 = mt8 * 256;

    // staging sources (bytes): K-tile stride 16384 B in each array
    const char* ga0 = (const char*)(x_p + (2 * mt8 + 0) * 65536) + tid * 16;
    const char* ga1 = (const char*)(x_p + (2 * mt8 + 1) * 65536) + tid * 16;
    const char* gb  = (const char*)(w_p + pair * 65536) + tid * 16;

    // per-thread frag read bases (bytes within a buffer); full addr =
    // buf + aoff + ks*4096 + mb*512   (A: slab=wm>>1, row=(wm&1)*64+mb*32+l31)
    // buf + boff + ks*4096 + nb*512   (B: col half wn)
    const int aoff = (wm >> 1) * 16384 + kh * 2048 + ((wm & 1) * 64 + lane31) * 16;
    const int boff = 32768 + kh * 2048 + (wn * 64 + lane31) * 16;

    f32x16 acc[2][2];
    #pragma unroll
    for (int mb = 0; mb < 2; ++mb)
        #pragma unroll
        for (int nb = 0; nb < 2; ++nb)
            acc[mb][nb] = (f32x16)(0.f);

#define STAGE(kt, base) do {                                               \
        gload_lds16(ga0 + (kt) * 16384,        (base) + tid * 16);         \
        gload_lds16(ga0 + (kt) * 16384 + 8192, (base) + 8192  + tid * 16); \
        gload_lds16(ga1 + (kt) * 16384,        (base) + 16384 + tid * 16); \
        gload_lds16(ga1 + (kt) * 16384 + 8192, (base) + 24576 + tid * 16); \
        gload_lds16(gb  + (kt) * 16384,        (base) + 32768 + tid * 16); \
        gload_lds16(gb  + (kt) * 16384 + 8192, (base) + 40960 + tid * 16); \
    } while (0)

    char* b0 = smem;             // holds K-tile kt
    char* b1 = smem + 49152;     // holds K-tile kt+1 (loads may be in flight)
    char* b2 = smem + 98304;     // stage target for kt+2

    STAGE(0, b0);
    STAGE(1, b1);

    // ---- K loop: 8 K-tiles of 64; counted vmcnt, loads span barriers ----
    // Top of iter kt: outstanding = [KT(kt):6, KT(kt+1):6]. vmcnt(6) lands
    // KT(kt) (FIFO), leaves KT(kt+1) in flight across the barrier.
    #pragma unroll
    for (int kt = 0; kt < 8; ++kt) {
        if (kt < 7) asm volatile("s_waitcnt vmcnt(6)" ::: "memory");
        else        asm volatile("s_waitcnt vmcnt(0)" ::: "memory");
        __builtin_amdgcn_s_barrier();      // all waves staged(kt); all reads
                                           // of b2's old content done (kt-1)
        if (kt < 6) STAGE(kt + 2, b2);
        __builtin_amdgcn_s_setprio(1);
        #pragma unroll
        for (int ks = 0; ks < 4; ++ks) {
            bf16x8 av0 = *(const bf16x8*)(b0 + aoff + ks * 4096);
            bf16x8 av1 = *(const bf16x8*)(b0 + aoff + ks * 4096 + 512);
            bf16x8 bv0 = *(const bf16x8*)(b0 + boff + ks * 4096);
            bf16x8 bv1 = *(const bf16x8*)(b0 + boff + ks * 4096 + 512);
            acc[0][0] = __builtin_amdgcn_mfma_f32_32x32x16_bf16(av0, bv0, acc[0][0], 0, 0, 0);
            acc[0][1] = __builtin_amdgcn_mfma_f32_32x32x16_bf16(av0, bv1, acc[0][1], 0, 0, 0);
            acc[1][0] = __builtin_amdgcn_mfma_f32_32x32x16_bf16(av1, bv0, acc[1][0], 0, 0, 0);
            acc[1][1] = __builtin_amdgcn_mfma_f32_32x32x16_bf16(av1, bv1, acc[1][1], 0, 0, 0);
        }
        __builtin_amdgcn_s_setprio(0);
        // rotate (fully unrolled -> pure renames)
        char* t = b0; b0 = b1; b1 = b2; b2 = t;
    }

    __syncthreads();                                 // K-loop reads done

    // ---- epilogue: h = relu(acc + b_t) -> H LDS; acc dies here ----
    // C/D layout (32x32): col = lane&31, row = (r&3) + 8*(r>>2) + 4*(lane>>5)
    #pragma unroll
    for (int nb = 0; nb < 2; ++nb) {
        float btv = b_t[(t0 + wn) * 64 + nb * 32 + lane31];
        #pragma unroll
        for (int mb = 0; mb < 2; ++mb)
            #pragma unroll
            for (int r = 0; r < 16; ++r) {
                int m = wm * 64 + mb * 32 + (r & 3) + 8 * (r >> 2) + 4 * kh;
                float hv = fmaxf(acc[mb][nb][r] + btv, 0.f);
                Hb[(wn * 256 + m) * 68 + nb * 32 + lane31] = (__bf16)hv;
            }
    }
    __syncthreads();                                 // H complete, both trees

    // ---- GEMM2: wave (wm,wn): logit[64 m x 16 l] for tree wn, K=64 ----
    f32x16 acc2[2] = { (f32x16)(0.f), (f32x16)(0.f) };
    const unsigned short* pW = w_dt + (t0 + wn) * 2048 + lane31 * 64 + kh * 8;
    __builtin_amdgcn_s_setprio(1);
    #pragma unroll
    for (int s = 0; s < 4; ++s) {
        bf16x8 bv = *(const bf16x8*)(pW + s * 16);
        #pragma unroll
        for (int i = 0; i < 2; ++i) {
            const unsigned short* pH =
                Hs + (wn * 256 + wm * 64 + i * 32 + lane31) * 68 + s * 16 + kh * 8;
            bf16x8 av = *(const bf16x8*)pH;
            acc2[i] = __builtin_amdgcn_mfma_f32_32x32x16_bf16(av, bv, acc2[i], 0, 0, 0);
        }
    }
    __builtin_amdgcn_s_setprio(0);
    __syncthreads();                                 // H reads done (P overlays H)

    // ---- p = sigmoid(logit + b_d) -> P [2][256][17] f32 ----
    if (lane31 < 15) {
        float bdv = b_d[(t0 + wn) * 15 + lane31];
        #pragma unroll
        for (int i = 0; i < 2; ++i)
            #pragma unroll
            for (int r = 0; r < 16; ++r) {
                int m = wm * 64 + i * 32 + (r & 3) + 8 * (r >> 2) + 4 * kh;
                float lg = acc2[i][r] + bdv;
                Pf[(wn * 256 + m) * 17 + lane31] = 1.f / (1.f + __expf(-lg));
            }
    }
    __syncthreads();

    // ---- soft routing + leaf score: thread = (tree j, row m) ----
    {
        int m = tid & 255;
        int j = tid >> 8;
        int t = t0 + j;
        float pv[15];
        #pragma unroll
        for (int i = 0; i < 15; ++i) pv[i] = Pf[(j * 256 + m) * 17 + i];
        float facc = 0.f;
        #pragma unroll
        for (int leaf = 0; leaf < 16; ++leaf) {
            float mu = 1.f;
            int node = 0;
            #pragma unroll
            for (int d = 0; d < 4; ++d) {
                int bit = (leaf >> (3 - d)) & 1;
                float p = pv[node];
                mu *= bit ? (1.f - p) : p;
                node = 2 * node + 1 + bit;
            }
            facc += mu * w_l[t * 16 + leaf];
        }
        f_ws[(m0 + m) * T_TREES + t] = tanhf(facc + b_l[t]);   // b-major
    }
#undef STAGE
}

// ---------------- boosting prefix-sum ----------------
// One WAVE per batch row (4 rows/block, grid 512). Lane l (l<50) owns
// trees 4l..4l+3 via one float4 load; local prefix-4 + 6-step shuffle
// inclusive scan of lane sums. No LDS, no __syncthreads.
__global__ __launch_bounds__(256) void scan_k(const float* __restrict__ f_ws,
                                              const float* __restrict__ f0p,
                                              float* __restrict__ out) {
    int lane = threadIdx.x & 63, wid = threadIdx.x >> 6;
    int b = blockIdx.x * 4 + wid;
    float f0 = f0p[0];
    float4 v;
    if (lane < 50) v = *(const float4*)(f_ws + b * T_TREES + lane * 4);
    else           v = make_float4(0.f, 0.f, 0.f, 0.f);
    float p0 = v.x;
    float p1 = p0 + v.y;
    float p2 = p1 + v.z;
    float p3 = p2 + v.w;
    float s = p3;
    #pragma unroll
    for (int off = 1; off < 64; off <<= 1) {
        float y = __shfl_up(s, off, 64);
        if (lane >= off) s += y;
    }
    float excl = s - p3;                 // exclusive prefix of lane sums
    if (lane < 50) {
        float* o = out + b * (T_TREES + 1) + 1 + lane * 4;
        o[0] = f0 + LR * (excl + p0);
        o[1] = f0 + LR * (excl + p1);
        o[2] = f0 + LR * (excl + p2);
        o[3] = f0 + LR * (excl + p3);
    }
    if (lane == 0) out[b * (T_TREES + 1)] = f0;
}

extern "C" void kernel_launch(void* const* d_in, const int* in_sizes, int n_in,
                              void* d_out, int out_size, void* d_ws, size_t ws_size,
                              hipStream_t stream) {
    const float* x   = (const float*)d_in[0];
    const float* w_t = (const float*)d_in[2];
    const float* b_t = (const float*)d_in[3];
    const float* w_d = (const float*)d_in[4];
    const float* b_d = (const float*)d_in[5];
    const float* w_l = (const float*)d_in[6];
    const float* b_l = (const float*)d_in[7];
    const float* f_0 = (const float*)d_in[8];
    float* out = (float*)d_out;

    char* ws = (char*)d_ws;
    unsigned short* x_p  = (unsigned short*)(ws);               // 2,097,152 B
    unsigned short* w_p  = (unsigned short*)(ws + 2097152);     // 13,107,200 B
    unsigned short* w_dt = (unsigned short*)(ws + 15204352);    //   819,200 B
    float*          f_ws = (float*)(ws + 16023552);             // 1,638,400 B

    prep_all<<<3456, 256, 0, stream>>>(x, w_t, w_d, x_p, w_p, w_dt);
    gbdt_main<<<832, 512, 0, stream>>>(x_p, w_p, w_dt, b_t, b_d, w_l, b_l, f_ws);
    scan_k<<<512, 256, 0, stream>>>(f_ws, f_0, out);
}

// Round 8
// 129.921 us; speedup vs baseline: 1.1276x; 1.1276x over previous
//
#include <hip/hip_runtime.h>

// Problem constants (from reference)
#define T_TREES 200
#define BATCH   2048
#define D_FEAT  512
#define N_NODE  64
#define LR      0.01f

typedef __attribute__((__ext_vector_type__(8)))  __bf16 bf16x8;
typedef __attribute__((__ext_vector_type__(16))) float  f32x16;

__device__ __forceinline__ unsigned short f32_to_bf16(float f) {
    unsigned u = __float_as_uint(f);
    u += 0x7FFFu + ((u >> 16) & 1u);   // RNE
    return (unsigned short)(u >> 16);
}

__device__ __forceinline__ void gload_lds16(const void* g, void* l) {
    __builtin_amdgcn_global_load_lds(
        (__attribute__((address_space(1))) void*)(void*)g,
        (__attribute__((address_space(3))) void*)l,
        16, 0, 0);
}

// ---------------- fused prep kernel ----------------
// kg-major layouts so main-kernel access is contiguous:
// x_p[mt 16][kg 64][m 128][8k] bf16 ; w_p[pair 100][kg 64][n' 128][8k] bf16 ;
// w_dt[t 200][32 node][64 n] bf16.
// XCD-AFFINE PLACEMENT (r6 post-mortem): gbdt_main's FETCH_SIZE ~= 15.1 MB
// == x_p + w_p + w_dt every round -> main's B-stream is an HBM cold-miss
// stream (~900 cyc): prep wrote w_p on round-robin XCDs, main reads it on
// XCD pair/13, and per-XCD L2s are not cross-coherent-fast. Remap the wt
// and wd sections so the WRITER runs on the READER's XCD (blockIdx%8 ==
// pair/13); dirty lines (1.64 MB/XCD) then serve main's reads as L2 hits.
// Grid 3584: [0,256) prep_x | [256,1920) prep_wt | [1920,3584) prep_wd.
__global__ __launch_bounds__(256) void prep_all(
    const float* __restrict__ x, const float* __restrict__ w_t,
    const float* __restrict__ w_d,
    unsigned short* __restrict__ x_p, unsigned short* __restrict__ w_p,
    unsigned short* __restrict__ w_dt) {
    __shared__ float tile[64 * 65];
    int b = blockIdx.x;
    if (b < 256) {
        // ---- x [2048][512] f32 -> x_p ----  (read by all XCDs; no affinity)
        int mb = b >> 3, slab = b & 7;
        const float* src = x + (mb * 64) * D_FEAT + slab * 64;
        #pragma unroll
        for (int p = 0; p < 16; ++p) {
            int idx = p * 256 + threadIdx.x;
            int r = idx >> 6, c = idx & 63;
            tile[r * 65 + c] = src[r * D_FEAT + c];
        }
        __syncthreads();
        int mt = mb >> 1, mq = mb & 1;
        unsigned short* dst = x_p + mt * 65536 + slab * 8192 + mq * 512;
        #pragma unroll
        for (int p = 0; p < 2; ++p) {
            int sid = p * 256 + threadIdx.x;   // 0..511
            int kgl = sid >> 6;                 // 0..7
            int r   = sid & 63;
            const float* sr = &tile[r * 65 + kgl * 8];
            bf16x8 o;
            #pragma unroll
            for (int j = 0; j < 8; ++j) o[j] = (__bf16)sr[j];
            *(bf16x8*)(dst + kgl * 1024 + r * 8) = o;
        }
    } else if (b < 1920) {
        // ---- w_t [t][d][n] f32 -> w_p, XCD-affine: xcd g owns pairs
        // [13g, 13g+13). b-256 = j*8 + g (256%8==0 -> g = b&7).
        int g  = b & 7;
        int j  = (b - 256) >> 3;     // 0..207
        int pj = j >> 4;             // 0..12
        int r8 = j & 15;
        int tq = r8 >> 3, slab = r8 & 7;
        int pair = g * 13 + pj;
        if (pair >= 100) return;
        int t = pair * 2 + tq;
        const float* src = w_t + t * (D_FEAT * N_NODE) + slab * 64 * N_NODE;
        #pragma unroll
        for (int p = 0; p < 16; ++p) {
            int idx = p * 256 + threadIdx.x;
            int d = idx >> 6, n = idx & 63;
            tile[d * 65 + n] = src[d * N_NODE + n];
        }
        __syncthreads();
        unsigned short* dst = w_p + pair * 65536 + slab * 8192 + tq * 512;
        #pragma unroll
        for (int p = 0; p < 2; ++p) {
            int sid = p * 256 + threadIdx.x;   // 0..511
            int kgl = sid >> 6;                 // 0..7
            int n   = sid & 63;
            bf16x8 o;
            #pragma unroll
            for (int j2 = 0; j2 < 8; ++j2) o[j2] = (__bf16)tile[(kgl * 8 + j2) * 65 + n];
            *(bf16x8*)(dst + kgl * 1024 + n * 8) = o;
        }
    } else {
        // ---- w_d [t][n][15] f32 -> w_dt [t][32][64], XCD-affine:
        // xcd g owns trees [26g, 26g+26); 8 blocks per tree.
        int g = b & 7;               // 1920%8==0
        int j = (b - 1920) >> 3;     // 0..207
        int t = g * 26 + (j >> 3);
        if (t >= 200) return;
        int sub = j & 7;
        int e = t * 2048 + sub * 256 + threadIdx.x;
        int n = e & 63;
        int l = (e >> 6) & 31;
        float v = (l < 15) ? w_d[(t * 64 + n) * 15 + l] : 0.f;
        w_dt[e] = f32_to_bf16(v);
    }
}

// ---------------- main fused kernel ----------------
// BYTE-IDENTICAL to round 4 (measured 45.16 µs, MfmaUtil 25%): block =
// 2 trees x 128 rows, 4 waves, A register-direct ping-pong, B 3-buf
// global_load_lds with counted vmcnt(2) (B(c+1) in flight across the
// barrier). This round's variable is prep's XCD-affine placement only.
__global__ __launch_bounds__(256, 4) void gbdt_main(
    const unsigned short* __restrict__ x_p,    // [16][64][128][8] bf16
    const unsigned short* __restrict__ w_p,    // [100][64][128][8] bf16
    const unsigned short* __restrict__ w_dt,   // [200][32][64] bf16
    const float* __restrict__ b_t,             // [200][64]
    const float* __restrict__ b_d,             // [200][15]
    const float* __restrict__ w_l,             // [200][16]
    const float* __restrict__ b_l,             // [200]
    float* __restrict__ f_ws)                  // [2048][200]  (b-major)
{
    // LDS: B bufs at 0/8192/16384 (chunk = [4 kg][128 n'][8k] bf16 = 8 KB).
    // Overlays after GEMM1: H [0,34816) = [2 tree][128 m][68 col] bf16
    // (136 B stride: 2-way bank alias on GEMM2 frag reads = free);
    // P [0,17408) = [2][128][17] f32.
    __shared__ alignas(16) char smem[34816];
    unsigned short* Hs = (unsigned short*)smem;
    __bf16*         Hb = (__bf16*)smem;
    float*          Pf = (float*)smem;

    const int tid    = threadIdx.x;
    const int lane   = tid & 63;
    const int w      = tid >> 6;
    const int lane31 = lane & 31;
    const int kh     = lane >> 5;
    const int wm     = w >> 1;       // row-half (0/1)
    const int wn     = w & 1;        // tree-in-pair (0/1)

    const int xcd  = blockIdx.x & 7;
    const int slot = blockIdx.x >> 3;     // 0..207
    const int mt   = slot & 15;           // 128-row tile
    const int pj   = slot >> 4;           // 0..12
    const int pair = xcd * 13 + pj;
    if (pair >= 100) return;
    const int t0 = pair * 2;
    const int m0 = mt * 128;

    // A frag base (elems): frag(c,s2,mb) at pA + c*4096 + s2*2048 + mb*256
    const unsigned short* pA = x_p + mt * 65536 + kh * 1024 + (wm * 64 + lane31) * 8;
    // B staging source (bytes): chunk stride 8192 B
    const char* gb = (const char*)(w_p + pair * 65536) + tid * 16;

    // per-thread B frag read base (bytes, within a chunk buffer)
    const int boff = kh * 2048 + (wn * 64 + lane31) * 16;

    f32x16 acc[2][2];
    #pragma unroll
    for (int mb = 0; mb < 2; ++mb)
        #pragma unroll
        for (int nb = 0; nb < 2; ++nb)
            acc[mb][nb] = (f32x16)(0.f);

#define LOAD_A(cn, areg) do {                                      \
        _Pragma("unroll")                                          \
        for (int s2 = 0; s2 < 2; ++s2)                             \
            _Pragma("unroll")                                      \
            for (int mb = 0; mb < 2; ++mb)                         \
                (areg)[s2 * 2 + mb] =                              \
                    *(const bf16x8*)(pA + (cn) * 4096 + s2 * 2048 + mb * 256); \
    } while (0)

#define STAGE_B(cn, base) do {                                            \
        gload_lds16(gb + (cn) * 8192,        (base) + tid * 16);          \
        gload_lds16(gb + (cn) * 8192 + 4096, (base) + tid * 16 + 4096);   \
    } while (0)

    bf16x8 aC[4], aN[4];
    LOAD_A(0, aC);
    STAGE_B(0, smem);
    STAGE_B(1, smem + 8192);

    char* rd  = smem;            // buffer holding chunk c
    char* rd1 = smem + 8192;     // buffer holding chunk c+1 (in flight ok)
    char* st2 = smem + 16384;    // stage target for chunk c+2

    // ---- K loop: 16 chunks of 32; counted vmcnt, loads span barriers ----
    #pragma unroll
    for (int c = 0; c < 16; ++c) {
        if (c < 15) asm volatile("s_waitcnt vmcnt(2)" ::: "memory");
        else        asm volatile("s_waitcnt vmcnt(0)" ::: "memory");
        __builtin_amdgcn_s_barrier();        // all waves: B(c) staged; readers
                                             // of st2's old content long done
        if (c < 15) LOAD_A(c + 1, aN);
        if (c < 14) STAGE_B(c + 2, st2);
        __builtin_amdgcn_s_setprio(1);
        #pragma unroll
        for (int s2 = 0; s2 < 2; ++s2) {
            bf16x8 bv0 = *(const bf16x8*)(rd + boff + s2 * 4096);
            bf16x8 bv1 = *(const bf16x8*)(rd + boff + s2 * 4096 + 512);
            acc[0][0] = __builtin_amdgcn_mfma_f32_32x32x16_bf16(aC[s2 * 2 + 0], bv0, acc[0][0], 0, 0, 0);
            acc[0][1] = __builtin_amdgcn_mfma_f32_32x32x16_bf16(aC[s2 * 2 + 0], bv1, acc[0][1], 0, 0, 0);
            acc[1][0] = __builtin_amdgcn_mfma_f32_32x32x16_bf16(aC[s2 * 2 + 1], bv0, acc[1][0], 0, 0, 0);
            acc[1][1] = __builtin_amdgcn_mfma_f32_32x32x16_bf16(aC[s2 * 2 + 1], bv1, acc[1][1], 0, 0, 0);
        }
        __builtin_amdgcn_s_setprio(0);
        // rotate (fully unrolled -> pure renames, no moves)
        char* t = rd; rd = rd1; rd1 = st2; st2 = t;
        #pragma unroll
        for (int i = 0; i < 4; ++i) aC[i] = aN[i];
    }

    __syncthreads();                                 // last B frag reads done

    // ---- epilogue: h = relu(acc + b_t) -> H LDS; acc dies here ----
    // C/D layout (32x32): col = lane&31, row = (r&3) + 8*(r>>2) + 4*(lane>>5)
    #pragma unroll
    for (int nb = 0; nb < 2; ++nb) {
        float btv = b_t[(t0 + wn) * 64 + nb * 32 + lane31];
        #pragma unroll
        for (int mb = 0; mb < 2; ++mb)
            #pragma unroll
            for (int r = 0; r < 16; ++r) {
                int m = wm * 64 + mb * 32 + (r & 3) + 8 * (r >> 2) + 4 * kh;
                float h = fmaxf(acc[mb][nb][r] + btv, 0.f);
                Hb[wn * 8704 + m * 68 + nb * 32 + lane31] = (__bf16)h;
            }
    }
    __syncthreads();                                 // H complete for both trees

    // ---- GEMM2: wave (wm,wn): logit[64 m x 16 l] for tree wn, K=64 ----
    f32x16 acc2[2] = { (f32x16)(0.f), (f32x16)(0.f) };
    const unsigned short* pW = w_dt + (t0 + wn) * 2048 + lane31 * 64 + kh * 8;
    __builtin_amdgcn_s_setprio(1);
    #pragma unroll
    for (int s = 0; s < 4; ++s) {
        bf16x8 bv = *(const bf16x8*)(pW + s * 16);
        #pragma unroll
        for (int i = 0; i < 2; ++i) {
            const unsigned short* pH =
                Hs + wn * 8704 + (wm * 64 + i * 32 + lane31) * 68 + s * 16 + kh * 8;
            bf16x8 av = *(const bf16x8*)pH;
            acc2[i] = __builtin_amdgcn_mfma_f32_32x32x16_bf16(av, bv, acc2[i], 0, 0, 0);
        }
    }
    __builtin_amdgcn_s_setprio(0);
    __syncthreads();                                 // H reads done (P overlays H)

    // ---- p = sigmoid(logit + b_d) -> P [2][128][17] f32 ----
    if (lane31 < 15) {
        float bdv = b_d[(t0 + wn) * 15 + lane31];
        #pragma unroll
        for (int i = 0; i < 2; ++i)
            #pragma unroll
            for (int r = 0; r < 16; ++r) {
                int m = wm * 64 + i * 32 + (r & 3) + 8 * (r >> 2) + 4 * kh;
                float lg = acc2[i][r] + bdv;
                Pf[(wn * 128 + m) * 17 + lane31] = 1.f / (1.f + __expf(-lg));
            }
    }
    __syncthreads();

    // ---- soft routing + leaf score: thread = (tree j, row m) ----
    {
        int m = tid & 127;
        int j = tid >> 7;
        int t = t0 + j;
        float pv[15];
        #pragma unroll
        for (int i = 0; i < 15; ++i) pv[i] = Pf[(j * 128 + m) * 17 + i];
        float facc = 0.f;
        #pragma unroll
        for (int leaf = 0; leaf < 16; ++leaf) {
            float mu = 1.f;
            int node = 0;
            #pragma unroll
            for (int d = 0; d < 4; ++d) {
                int bit = (leaf >> (3 - d)) & 1;
                float p = pv[node];
                mu *= bit ? (1.f - p) : p;
                node = 2 * node + 1 + bit;
            }
            facc += mu * w_l[t * 16 + leaf];
        }
        f_ws[(m0 + m) * T_TREES + t] = tanhf(facc + b_l[t]);   // b-major
    }
#undef STAGE_B
#undef LOAD_A
}

// ---------------- boosting prefix-sum ----------------
// One WAVE per batch row (4 rows/block, grid 512). Lane l (l<50) owns
// trees 4l..4l+3 via one float4 load; local prefix-4 + 6-step shuffle
// inclusive scan of lane sums. No LDS, no __syncthreads.
__global__ __launch_bounds__(256) void scan_k(const float* __restrict__ f_ws,
                                              const float* __restrict__ f0p,
                                              float* __restrict__ out) {
    int lane = threadIdx.x & 63, wid = threadIdx.x >> 6;
    int b = blockIdx.x * 4 + wid;
    float f0 = f0p[0];
    float4 v;
    if (lane < 50) v = *(const float4*)(f_ws + b * T_TREES + lane * 4);
    else           v = make_float4(0.f, 0.f, 0.f, 0.f);
    float p0 = v.x;
    float p1 = p0 + v.y;
    float p2 = p1 + v.z;
    float p3 = p2 + v.w;
    float s = p3;
    #pragma unroll
    for (int off = 1; off < 64; off <<= 1) {
        float y = __shfl_up(s, off, 64);
        if (lane >= off) s += y;
    }
    float excl = s - p3;                 // exclusive prefix of lane sums
    if (lane < 50) {
        float* o = out + b * (T_TREES + 1) + 1 + lane * 4;
        o[0] = f0 + LR * (excl + p0);
        o[1] = f0 + LR * (excl + p1);
        o[2] = f0 + LR * (excl + p2);
        o[3] = f0 + LR * (excl + p3);
    }
    if (lane == 0) out[b * (T_TREES + 1)] = f0;
}

extern "C" void kernel_launch(void* const* d_in, const int* in_sizes, int n_in,
                              void* d_out, int out_size, void* d_ws, size_t ws_size,
                              hipStream_t stream) {
    const float* x   = (const float*)d_in[0];
    const float* w_t = (const float*)d_in[2];
    const float* b_t = (const float*)d_in[3];
    const float* w_d = (const float*)d_in[4];
    const float* b_d = (const float*)d_in[5];
    const float* w_l = (const float*)d_in[6];
    const float* b_l = (const float*)d_in[7];
    const float* f_0 = (const float*)d_in[8];
    float* out = (float*)d_out;

    char* ws = (char*)d_ws;
    unsigned short* x_p  = (unsigned short*)(ws);               // 2,097,152 B
    unsigned short* w_p  = (unsigned short*)(ws + 2097152);     // 13,107,200 B
    unsigned short* w_dt = (unsigned short*)(ws + 15204352);    //   819,200 B
    float*          f_ws = (float*)(ws + 16023552);             // 1,638,400 B

    prep_all<<<3584, 256, 0, stream>>>(x, w_t, w_d, x_p, w_p, w_dt);
    gbdt_main<<<1664, 256, 0, stream>>>(x_p, w_p, w_dt, b_t, b_d, w_l, b_l, f_ws);
    scan_k<<<512, 256, 0, stream>>>(f_ws, f_0, out);
}